// Round 6
// baseline (285.995 us; speedup 1.0000x reference)
//
// resubmit of round-5 candidate — prior run failed on container acquisition, not kernel
#include <hip/hip_runtime.h>

typedef short bf16x8 __attribute__((ext_vector_type(8)));
typedef float f32x4 __attribute__((ext_vector_type(4)));
typedef float f32x2 __attribute__((ext_vector_type(2)));

#define NN 10000
#define EE 160000
#define BB 4
#define TTT 12
#define FFF 16
#define CCC 64
#define BT 48      // BB*TTT
#define NF 768     // BT*FFF
#define SLOTS 64   // padded adjacency slots per node (P[deg>64] ~ 1e-20 for Poisson(16))

#define TCS 72     // tcat row stride (bf16); 144B = 9x16B -> uint4 rows stay 16B-aligned
#define SPS 80     // sp row stride (bf16) — empirically fewer conflicts than 72
#define HMS 68     // hmat row stride (f32)

// workspace byte offsets (256B aligned)
#define WS_DEG     0u                  // float[10000]
#define WS_CNT     40960u              // int[10000] (atomic cursors -> final = in-deg)
#define WS_CWT     81920u              // ushort[4096]
#define WS_RWTB    90112u              // ushort[2048]
#define WS_WKT     94208u              // ushort[12288]
#define WS_CSRP    118784u             // int[10000*64], memset 0x7F -> clamp to NN
#define WS_VBF     2678784u            // ushort[10001*768]
#define WS_TX1BF   18040320u           // ushort[10001*768]  (ends ~33.4 MB)

__device__ __forceinline__ unsigned short f2bf(float x){
    unsigned int u = __float_as_uint(x);
    u += 0x7FFFu + ((u >> 16) & 1u);
    return (unsigned short)(u >> 16);
}
__device__ __forceinline__ float bf2f(unsigned short h){
    return __uint_as_float(((unsigned int)h) << 16);
}
__device__ __forceinline__ unsigned int pk2bf(float lo, float hi){
    return (unsigned int)f2bf(lo) | ((unsigned int)f2bf(hi) << 16);
}

// clamp pad slots (0x7F7F7F7F from memset) to the dummy zero row NN
#define GMIN4(E)                                                                  \
    E.x = E.x < NN ? E.x : NN; E.y = E.y < NN ? E.y : NN;                         \
    E.z = E.z < NN ? E.z : NN; E.w = E.w < NN ? E.w : NN;

// accumulate one 16B chunk (8 bf16) into 4 packed-f32 accumulators
__device__ __forceinline__ void accpk4(const uint4& d, f32x2& A0, f32x2& A1,
                                       f32x2& A2, f32x2& A3){
    f32x2 t;
    t.x = __uint_as_float(d.x << 16); t.y = __uint_as_float(d.x & 0xFFFF0000u); A0 += t;
    t.x = __uint_as_float(d.y << 16); t.y = __uint_as_float(d.y & 0xFFFF0000u); A1 += t;
    t.x = __uint_as_float(d.z << 16); t.y = __uint_as_float(d.z & 0xFFFF0000u); A2 += t;
    t.x = __uint_as_float(d.w << 16); t.y = __uint_as_float(d.w & 0xFFFF0000u); A3 += t;
}

// 16 neighbors x 16B per lane, in flight together; two accumulator banks (A,B)
#define GATHER16X16(SRC, E0, E1, E2, E3, A0, A1, A2, A3, B0, B1, B2, B3, FO)      \
    {                                                                             \
        uint4 d0 = *(const uint4*)&SRC[(size_t)E0.x * NF + (FO)];                 \
        uint4 d1 = *(const uint4*)&SRC[(size_t)E0.y * NF + (FO)];                 \
        uint4 d2 = *(const uint4*)&SRC[(size_t)E0.z * NF + (FO)];                 \
        uint4 d3 = *(const uint4*)&SRC[(size_t)E0.w * NF + (FO)];                 \
        uint4 d4 = *(const uint4*)&SRC[(size_t)E1.x * NF + (FO)];                 \
        uint4 d5 = *(const uint4*)&SRC[(size_t)E1.y * NF + (FO)];                 \
        uint4 d6 = *(const uint4*)&SRC[(size_t)E1.z * NF + (FO)];                 \
        uint4 d7 = *(const uint4*)&SRC[(size_t)E1.w * NF + (FO)];                 \
        uint4 d8 = *(const uint4*)&SRC[(size_t)E2.x * NF + (FO)];                 \
        uint4 d9 = *(const uint4*)&SRC[(size_t)E2.y * NF + (FO)];                 \
        uint4 da = *(const uint4*)&SRC[(size_t)E2.z * NF + (FO)];                 \
        uint4 db = *(const uint4*)&SRC[(size_t)E2.w * NF + (FO)];                 \
        uint4 dc = *(const uint4*)&SRC[(size_t)E3.x * NF + (FO)];                 \
        uint4 dd = *(const uint4*)&SRC[(size_t)E3.y * NF + (FO)];                 \
        uint4 de = *(const uint4*)&SRC[(size_t)E3.z * NF + (FO)];                 \
        uint4 df = *(const uint4*)&SRC[(size_t)E3.w * NF + (FO)];                 \
        accpk4(d0, A0, A1, A2, A3); accpk4(d1, A0, A1, A2, A3);                   \
        accpk4(d2, A0, A1, A2, A3); accpk4(d3, A0, A1, A2, A3);                   \
        accpk4(d4, A0, A1, A2, A3); accpk4(d5, A0, A1, A2, A3);                   \
        accpk4(d6, A0, A1, A2, A3); accpk4(d7, A0, A1, A2, A3);                   \
        accpk4(d8, B0, B1, B2, B3); accpk4(d9, B0, B1, B2, B3);                   \
        accpk4(da, B0, B1, B2, B3); accpk4(db, B0, B1, B2, B3);                   \
        accpk4(dc, B0, B1, B2, B3); accpk4(dd, B0, B1, B2, B3);                   \
        accpk4(de, B0, B1, B2, B3); accpk4(df, B0, B1, B2, B3);                   \
    }

// fused setup grid (1636 blocks):
//   [0,625)      single edge pass: deg atomic + fillpad atomic (merged)
//   [625,1563)   buildv: float2 register transpose, 24 threads/node
//   1563         zero dummy rows
//   [1564,1636)  weight transposes
__global__ __launch_bounds__(256) void k_setup(
    const float* __restrict__ x, const int* __restrict__ ei,
    const float* __restrict__ chW, const float* __restrict__ tW, const float* __restrict__ rW,
    float* __restrict__ deg, int* __restrict__ cnt, int* __restrict__ csrp,
    unsigned short* __restrict__ vbf, unsigned short* __restrict__ tx1bf,
    unsigned short* __restrict__ cWt, unsigned short* __restrict__ rWtb,
    unsigned short* __restrict__ wkt)
{
    int bid = blockIdx.x, tid = threadIdx.x;
    if (bid < 625){
        int e = bid * 256 + tid;
        if (e < EE){
            int r = ei[e];
            int c = ei[EE + e];
            atomicAdd(&deg[r], 1.0f);
            int slot = atomicAdd(&cnt[c], 1);
            if (slot < SLOTS) csrp[c * SLOTS + slot] = r;
        }
    } else if (bid < 1563){
        int u = (bid - 625) * 256 + tid;             // < 240000
        if (u < 240000){
            int n = u / 24, r = u - n * 24;
            int t2 = r >> 2, j = r & 3;              // times {2t2, 2t2+1}, channels 4j..4j+3
            #pragma unroll
            for (int b = 0; b < BB; ++b){
                const float* xp = x + (size_t)(b * NN + n) * 192;
                float2 v0 = *(const float2*)&xp[(4 * j + 0) * 12 + 2 * t2];
                float2 v1 = *(const float2*)&xp[(4 * j + 1) * 12 + 2 * t2];
                float2 v2 = *(const float2*)&xp[(4 * j + 2) * 12 + 2 * t2];
                float2 v3 = *(const float2*)&xp[(4 * j + 3) * 12 + 2 * t2];
                ushort4 w0 = { f2bf(v0.x), f2bf(v1.x), f2bf(v2.x), f2bf(v3.x) };
                ushort4 w1 = { f2bf(v0.y), f2bf(v1.y), f2bf(v2.y), f2bf(v3.y) };
                size_t base = (size_t)n * NF + b * 192 + (2 * t2) * 16 + j * 4;
                *(ushort4*)&vbf[base]      = w0;
                *(ushort4*)&vbf[base + 16] = w1;
            }
        }
    } else if (bid == 1563){
        if (tid < 192){
            ushort4 z = { 0, 0, 0, 0 };
            *(ushort4*)&vbf[(size_t)NN * NF + tid * 4]   = z;
            *(ushort4*)&tx1bf[(size_t)NN * NF + tid * 4] = z;
        }
    } else {
        int idx = (bid - 1564) * 256 + tid;          // < 18432
        if (idx < 4096){                      // cWt[c][k], k = kk*16+f (48 real, pad 0)
            int c = idx >> 6, k = idx & 63;
            float v = 0.f;
            if (k < 48){ int kk = k >> 4, f = k & 15; v = chW[kk * 1024 + f * 64 + c]; }
            cWt[idx] = f2bf(v);
        } else if (idx < 6144){               // rWtb[o][k], k<16 = f, pad 0
            int j = idx - 4096;
            int o = j >> 5, k = j & 31;
            float v = (k < 16) ? rW[o * 16 + k] : 0.f;
            rWtb[j] = f2bf(v);
        } else {                              // wkt[kk][o][dc]
            int j = idx - 6144;
            int kk = j >> 12; int r2 = j & 4095;
            int o = r2 >> 6, dc = r2 & 63;
            wkt[j] = f2bf(tW[(o * 64 + dc) * 3 + kk]);
        }
    }
}

// tx1 = (2/lam)*(deg*v - agg) - v
// 2 nodes/block, 96 lanes/node, 16 neighbors x 16B in flight per lane.
// Trip count is BLOCK-uniform (max of both nodes); pad slots read the zero
// dummy row so extra iterations add exact 0 -> no wave divergence.
__global__ __launch_bounds__(192) void k_lhat(
        const unsigned short* __restrict__ vbf, const float* __restrict__ deg,
        const int* __restrict__ cnt, const int* __restrict__ csrp,
        const float* __restrict__ lam, unsigned short* __restrict__ tx1bf){
    int tid = threadIdx.x;
    int h  = tid >= 96;
    int fb = tid - h * 96;
    int n  = blockIdx.x * 2 + h;
    int fo = fb * 8;
    float s2 = 2.0f / lam[0];
    float dn = deg[n];
    int cA = cnt[blockIdx.x * 2];     cA = cA > SLOTS ? SLOTS : cA;
    int cB = cnt[blockIdx.x * 2 + 1]; cB = cB > SLOTS ? SLOTS : cB;
    int cm = cA > cB ? cA : cB;
    int iters = (cm + 15) >> 4;
    const int4* cp = (const int4*)(csrp + n * SLOTS);
    f32x2 A0 = {0.f,0.f}, A1 = {0.f,0.f}, A2 = {0.f,0.f}, A3 = {0.f,0.f};
    f32x2 B0 = {0.f,0.f}, B1 = {0.f,0.f}, B2 = {0.f,0.f}, B3 = {0.f,0.f};
    for (int it = 0; it < iters; ++it){
        int4 e0 = cp[it * 4], e1 = cp[it * 4 + 1];
        int4 e2 = cp[it * 4 + 2], e3 = cp[it * 4 + 3];
        GMIN4(e0) GMIN4(e1) GMIN4(e2) GMIN4(e3)
        GATHER16X16(vbf, e0, e1, e2, e3, A0, A1, A2, A3, B0, B1, B2, B3, fo);
    }
    A0 += B0; A1 += B1; A2 += B2; A3 += B3;
    uint4 hv = *(const uint4*)&vbf[(size_t)n * NF + fo];
    uint4 o;
    {
        float vlo, vhi;
        vlo = __uint_as_float(hv.x << 16); vhi = __uint_as_float(hv.x & 0xFFFF0000u);
        o.x = pk2bf(s2 * (dn * vlo - A0.x) - vlo, s2 * (dn * vhi - A0.y) - vhi);
        vlo = __uint_as_float(hv.y << 16); vhi = __uint_as_float(hv.y & 0xFFFF0000u);
        o.y = pk2bf(s2 * (dn * vlo - A1.x) - vlo, s2 * (dn * vhi - A1.y) - vhi);
        vlo = __uint_as_float(hv.z << 16); vhi = __uint_as_float(hv.z & 0xFFFF0000u);
        o.z = pk2bf(s2 * (dn * vlo - A2.x) - vlo, s2 * (dn * vhi - A2.y) - vhi);
        vlo = __uint_as_float(hv.w << 16); vhi = __uint_as_float(hv.w & 0xFFFF0000u);
        o.w = pk2bf(s2 * (dn * vlo - A3.x) - vlo, s2 * (dn * vhi - A3.y) - vhi);
    }
    *(uint4*)&tx1bf[(size_t)n * NF + fo] = o;
}

// per-node fused: gather->Tcat(bf16) -> MFMA Cheb+resid -> sp(bf16) -> MFMA
// temporal conv -> hmat -> LayerNorm -> out
// LDS union: [spl | red] (8960B) + [tcat | hmat] (13056B) = 22016B
__global__ __launch_bounds__(256) void k_fused(
    const unsigned short* __restrict__ vbf, const unsigned short* __restrict__ tx1bf,
    const float* __restrict__ deg, const int* __restrict__ cnt, const int* __restrict__ csrp,
    const float* __restrict__ lam,
    const unsigned short* __restrict__ cWt, const float* __restrict__ chebB,
    const unsigned short* __restrict__ wkt, const float* __restrict__ timeB,
    const unsigned short* __restrict__ rWtb, const float* __restrict__ resB,
    const float* __restrict__ gamma, const float* __restrict__ beta,
    float* __restrict__ out)
{
    __shared__ __align__(16) char smem[22016];
    unsigned short* spl  = (unsigned short*)smem;            // 56*SPS bf16 (phases B-D)
    float2*         red  = (float2*)smem;                    // 48 float2 (overlays dead spl)
    unsigned short* tcat = (unsigned short*)(smem + 8960);   // 48*TCS bf16 (phases A-B)
    float*          hmat = (float*)(smem + 8960);            // 48*HMS f32 (phase D+, overlays tcat)

    int n = blockIdx.x;
    int tid = threadIdx.x;

    int lane = tid & 63;
    int nt   = tid >> 6;
    int ln   = lane & 15;
    int quad = lane >> 4;
    int q8   = quad * 8;
    int col  = nt * 16 + ln;

    // ---- zero sp pad rows (p=0, p=13 per b) ----
    {
        int rid = tid >> 5;
        int cc = tid & 31;
        int b = rid >> 1, p = (rid & 1) * 13;
        *(unsigned int*)&spl[(b * 14 + p) * SPS + cc * 2] = 0u;
    }

    // ---- phase A: 96-lane gather, 16 neighbors x 16B in flight, 1 round for deg<=16 ----
    if (tid < 96){
        int fb = tid, fo = fb * 8;
        float s2 = 2.0f / lam[0];
        float dn = deg[n];
        uint4 hv = *(const uint4*)&vbf[(size_t)n * NF + fo];
        uint4 hu = *(const uint4*)&tx1bf[(size_t)n * NF + fo];
        f32x2 A0 = {0.f,0.f}, A1 = {0.f,0.f}, A2 = {0.f,0.f}, A3 = {0.f,0.f};
        f32x2 B0 = {0.f,0.f}, B1 = {0.f,0.f}, B2 = {0.f,0.f}, B3 = {0.f,0.f};
        int c = cnt[n]; c = c > SLOTS ? SLOTS : c;
        int iters = (c + 15) >> 4;
        const int4* cp = (const int4*)(csrp + n * SLOTS);
        for (int it = 0; it < iters; ++it){
            int4 e0 = cp[it * 4], e1 = cp[it * 4 + 1];
            int4 e2 = cp[it * 4 + 2], e3 = cp[it * 4 + 3];
            GMIN4(e0) GMIN4(e1) GMIN4(e2) GMIN4(e3)
            GATHER16X16(tx1bf, e0, e1, e2, e3, A0, A1, A2, A3, B0, B1, B2, B3, fo);
        }
        A0 += B0; A1 += B1; A2 += B2; A3 += B3;
        uint4 w2;
        {
            float ulo, uhi, vlo, vhi;
            ulo = __uint_as_float(hu.x << 16); uhi = __uint_as_float(hu.x & 0xFFFF0000u);
            vlo = __uint_as_float(hv.x << 16); vhi = __uint_as_float(hv.x & 0xFFFF0000u);
            w2.x = pk2bf(2.0f * (s2 * (dn * ulo - A0.x) - ulo) - vlo,
                         2.0f * (s2 * (dn * uhi - A0.y) - uhi) - vhi);
            ulo = __uint_as_float(hu.y << 16); uhi = __uint_as_float(hu.y & 0xFFFF0000u);
            vlo = __uint_as_float(hv.y << 16); vhi = __uint_as_float(hv.y & 0xFFFF0000u);
            w2.y = pk2bf(2.0f * (s2 * (dn * ulo - A1.x) - ulo) - vlo,
                         2.0f * (s2 * (dn * uhi - A1.y) - uhi) - vhi);
            ulo = __uint_as_float(hu.z << 16); uhi = __uint_as_float(hu.z & 0xFFFF0000u);
            vlo = __uint_as_float(hv.z << 16); vhi = __uint_as_float(hv.z & 0xFFFF0000u);
            w2.z = pk2bf(2.0f * (s2 * (dn * ulo - A2.x) - ulo) - vlo,
                         2.0f * (s2 * (dn * uhi - A2.y) - uhi) - vhi);
            ulo = __uint_as_float(hu.w << 16); uhi = __uint_as_float(hu.w & 0xFFFF0000u);
            vlo = __uint_as_float(hv.w << 16); vhi = __uint_as_float(hv.w & 0xFFFF0000u);
            w2.w = pk2bf(2.0f * (s2 * (dn * ulo - A3.x) - ulo) - vlo,
                         2.0f * (s2 * (dn * uhi - A3.y) - uhi) - vhi);
        }
        // lane fb covers features [8fb, 8fb+8): tcat row fb>>1, col (fb&1)*8
        unsigned short* tr = &tcat[(fb >> 1) * TCS + (fb & 1) * 8];
        uint4 z = {0u, 0u, 0u, 0u};
        *(uint4*)&tr[0]  = hv;   // T0
        *(uint4*)&tr[16] = hu;   // T1
        *(uint4*)&tr[32] = w2;   // T2
        *(uint4*)&tr[48] = z;    // zero K-pad
    }
    __syncthreads();

    // ---- phase B: Cheb GEMM (K=64) + residual GEMM (weights loaded here, not hoisted) ----
    {
        bf16x8 cb0 = *(const bf16x8*)&cWt[col * 64 + q8];
        bf16x8 cb1 = *(const bf16x8*)&cWt[col * 64 + 32 + q8];
        bf16x8 rb  = *(const bf16x8*)&rWtb[col * 32 + q8];
        float cb = chebB[col];
        float tb = timeB[col] + resB[col];
        f32x4 cacc[3], racc[3];
        #pragma unroll
        for (int mt = 0; mt < 3; ++mt){
            bf16x8 a0 = *(const bf16x8*)&tcat[(mt * 16 + ln) * TCS + q8];
            bf16x8 a1 = *(const bf16x8*)&tcat[(mt * 16 + ln) * TCS + 32 + q8];
            f32x4 z = {0.f, 0.f, 0.f, 0.f};
            cacc[mt] = __builtin_amdgcn_mfma_f32_16x16x32_bf16(a0, cb0, z, 0, 0, 0);
            cacc[mt] = __builtin_amdgcn_mfma_f32_16x16x32_bf16(a1, cb1, cacc[mt], 0, 0, 0);
            racc[mt] = __builtin_amdgcn_mfma_f32_16x16x32_bf16(a0, rb, z, 0, 0, 0);
        }
        #pragma unroll
        for (int mt = 0; mt < 3; ++mt){
            #pragma unroll
            for (int i = 0; i < 4; ++i){
                int r = mt * 16 + quad * 4 + i;
                int bb = (r * 43) >> 9;
                int tt = r - 12 * bb;
                float val = fmaxf(cacc[mt][i] + cb, 0.0f);
                spl[(bb * 14 + tt + 1) * SPS + col] = f2bf(val);
            }
        }
        __syncthreads();   // tcat dead from here; hmat may overwrite it

        // ---- phase D: temporal conv = 3 shifted GEMMs ----
        bf16x8 wb[3][2];
        #pragma unroll
        for (int kk = 0; kk < 3; ++kk){
            wb[kk][0] = *(const bf16x8*)&wkt[kk * 4096 + col * 64 + q8];
            wb[kk][1] = *(const bf16x8*)&wkt[kk * 4096 + col * 64 + 32 + q8];
        }
        #pragma unroll
        for (int mt = 0; mt < 3; ++mt){
            int bt = mt * 16 + ln;
            int bb = (bt * 43) >> 9;
            int tt = bt - 12 * bb;
            int rbase = bb * 14 + tt;
            f32x4 tacc = {0.f, 0.f, 0.f, 0.f};
            #pragma unroll
            for (int kk = 0; kk < 3; ++kk){
                bf16x8 a0 = *(const bf16x8*)&spl[(rbase + kk) * SPS + q8];
                bf16x8 a1 = *(const bf16x8*)&spl[(rbase + kk) * SPS + 32 + q8];
                tacc = __builtin_amdgcn_mfma_f32_16x16x32_bf16(a0, wb[kk][0], tacc, 0, 0, 0);
                tacc = __builtin_amdgcn_mfma_f32_16x16x32_bf16(a1, wb[kk][1], tacc, 0, 0, 0);
            }
            #pragma unroll
            for (int i = 0; i < 4; ++i){
                int r = mt * 16 + quad * 4 + i;
                float h = fmaxf(tacc[i] + racc[mt][i] + tb, 0.0f);
                hmat[r * HMS + col] = h;
            }
        }
    }
    __syncthreads();   // spl dead from here; red may overwrite it

    // ---- LN partial sums: 4 lanes per row ----
    if (tid < 192){
        int row = tid >> 2, p = tid & 3;
        const float4* h4 = (const float4*)&hmat[row * HMS + p * 16];
        float4 A = h4[0], Bv = h4[1], Cv = h4[2], Dv = h4[3];
        float s = A.x+A.y+A.z+A.w + Bv.x+Bv.y+Bv.z+Bv.w
                + Cv.x+Cv.y+Cv.z+Cv.w + Dv.x+Dv.y+Dv.z+Dv.w;
        float q = A.x*A.x+A.y*A.y+A.z*A.z+A.w*A.w + Bv.x*Bv.x+Bv.y*Bv.y+Bv.z*Bv.z+Bv.w*Bv.w
                + Cv.x*Cv.x+Cv.y*Cv.y+Cv.z*Cv.z+Cv.w*Cv.w + Dv.x*Dv.x+Dv.y*Dv.y+Dv.z*Dv.z+Dv.w*Dv.w;
        s += __shfl_xor(s, 1); q += __shfl_xor(q, 1);
        s += __shfl_xor(s, 2); q += __shfl_xor(q, 2);
        if (p == 0) red[row] = make_float2(s, q);
    }
    __syncthreads();

    // ---- normalize + store ----
    {
        int g = nt, o = lane;
        float gam = gamma[o], bet = beta[o];
        float res[12];
        #pragma unroll
        for (int t = 0; t < 12; ++t){
            int row = g * 12 + t;
            float h = hmat[row * HMS + o];
            float2 m = red[row];
            float mu  = m.x * (1.0f / 64.0f);
            float var = m.y * (1.0f / 64.0f) - mu * mu;
            float r   = rsqrtf(var + 1e-5f);
            res[t] = (h - mu) * r * gam + bet;
        }
        size_t obase = ((size_t)(g * NN + n) * CCC + o) * TTT;
        float4* op = (float4*)(out + obase);
        op[0] = make_float4(res[0], res[1], res[2],  res[3]);
        op[1] = make_float4(res[4], res[5], res[6],  res[7]);
        op[2] = make_float4(res[8], res[9], res[10], res[11]);
    }
}

extern "C" void kernel_launch(void* const* d_in, const int* in_sizes, int n_in,
                              void* d_out, int out_size, void* d_ws, size_t ws_size,
                              hipStream_t stream)
{
    (void)in_sizes; (void)n_in; (void)out_size; (void)ws_size;
    const float* x   = (const float*)d_in[0];
    const int*   ei  = (const int*)  d_in[1];
    const float* lam = (const float*)d_in[2];
    const float* chW = (const float*)d_in[3];
    const float* chB = (const float*)d_in[4];
    const float* tW  = (const float*)d_in[5];
    const float* tB  = (const float*)d_in[6];
    const float* rW  = (const float*)d_in[7];
    const float* rB  = (const float*)d_in[8];
    const float* gam = (const float*)d_in[9];
    const float* bet = (const float*)d_in[10];
    float* out = (float*)d_out;

    char* ws = (char*)d_ws;
    float* deg  = (float*)(ws + WS_DEG);
    int*   cnt  = (int*)  (ws + WS_CNT);
    unsigned short* cWt  = (unsigned short*)(ws + WS_CWT);
    unsigned short* rWtb = (unsigned short*)(ws + WS_RWTB);
    unsigned short* wkt  = (unsigned short*)(ws + WS_WKT);
    int*   csrp = (int*)  (ws + WS_CSRP);
    unsigned short* vbf   = (unsigned short*)(ws + WS_VBF);
    unsigned short* tx1bf = (unsigned short*)(ws + WS_TX1BF);

    hipMemsetAsync(ws, 0, 81920, stream);                      // deg + cnt
    hipMemsetAsync(ws + WS_CSRP, 0x7F, NN * SLOTS * 4, stream); // csrp pad (clamped to NN)
    k_setup  <<<1636, 256, 0, stream>>>(x, ei, chW, tW, rW, deg, cnt, csrp,
                                        vbf, tx1bf, cWt, rWtb, wkt);
    k_lhat   <<<NN / 2, 192, 0, stream>>>(vbf, deg, cnt, csrp, lam, tx1bf);
    k_fused  <<<NN, 256, 0, stream>>>(vbf, tx1bf, deg, cnt, csrp, lam,
                                      cWt, chB, wkt, tB, rWtb, rB, gam, bet, out);
}

// Round 7
// 280.691 us; speedup vs baseline: 1.0189x; 1.0189x over previous
//
#include <hip/hip_runtime.h>

typedef short bf16x8 __attribute__((ext_vector_type(8)));
typedef float f32x4 __attribute__((ext_vector_type(4)));
typedef float f32x2 __attribute__((ext_vector_type(2)));

#define NN 10000
#define EE 160000
#define BB 4
#define TTT 12
#define FFF 16
#define CCC 64
#define BT 48      // BB*TTT
#define NF 768     // BT*FFF
#define SLOTS 64   // padded adjacency slots per node (P[deg>64] ~ 1e-20 for Poisson(16))

#define TCS 72     // tcat row stride (bf16)
#define SPS 80     // sp row stride (bf16) — empirically fewer conflicts than 72
#define HMS 68     // hmat row stride (f32)

// workspace byte offsets (256B aligned)
#define WS_DEG     0u                  // float[10000]
#define WS_CNT     40960u              // int[10000] (atomic cursors -> final = in-deg)
#define WS_CWT     81920u              // ushort[4096]
#define WS_RWTB    90112u              // ushort[2048]
#define WS_WKT     94208u              // ushort[12288]
#define WS_CSRP    118784u             // int[10000*64], memset 0x7F -> clamp to NN
#define WS_VBF     2678784u            // ushort[10001*768]
#define WS_TX1BF   18040320u           // ushort[10001*768]  (ends ~33.4 MB)

__device__ __forceinline__ unsigned short f2bf(float x){
    unsigned int u = __float_as_uint(x);
    u += 0x7FFFu + ((u >> 16) & 1u);
    return (unsigned short)(u >> 16);
}
__device__ __forceinline__ float bf2f(unsigned short h){
    return __uint_as_float(((unsigned int)h) << 16);
}
__device__ __forceinline__ unsigned int pk2bf(float lo, float hi){
    return (unsigned int)f2bf(lo) | ((unsigned int)f2bf(hi) << 16);
}

// clamp pad slots (0x7F7F7F7F from memset) to the dummy zero row NN
#define GMIN4(E)                                                                  \
    E.x = E.x < NN ? E.x : NN; E.y = E.y < NN ? E.y : NN;                         \
    E.z = E.z < NN ? E.z : NN; E.w = E.w < NN ? E.w : NN;

// r1-proven gather: 8 neighbors x 8B per lane, scalar bf16 unpack+add (89us config)
#define GATHER8(SRC, EA, EB, ACC0, ACC1, ACC2, ACC3, Q)                           \
    {                                                                             \
        ushort4 p0 = *(const ushort4*)&SRC[(size_t)EA.x * NF + (Q) * 4];          \
        ushort4 p1 = *(const ushort4*)&SRC[(size_t)EA.y * NF + (Q) * 4];          \
        ushort4 p2 = *(const ushort4*)&SRC[(size_t)EA.z * NF + (Q) * 4];          \
        ushort4 p3 = *(const ushort4*)&SRC[(size_t)EA.w * NF + (Q) * 4];          \
        ushort4 p4 = *(const ushort4*)&SRC[(size_t)EB.x * NF + (Q) * 4];          \
        ushort4 p5 = *(const ushort4*)&SRC[(size_t)EB.y * NF + (Q) * 4];          \
        ushort4 p6 = *(const ushort4*)&SRC[(size_t)EB.z * NF + (Q) * 4];          \
        ushort4 p7 = *(const ushort4*)&SRC[(size_t)EB.w * NF + (Q) * 4];          \
        ACC0 += bf2f(p0.x)+bf2f(p1.x)+bf2f(p2.x)+bf2f(p3.x)                       \
              + bf2f(p4.x)+bf2f(p5.x)+bf2f(p6.x)+bf2f(p7.x);                      \
        ACC1 += bf2f(p0.y)+bf2f(p1.y)+bf2f(p2.y)+bf2f(p3.y)                       \
              + bf2f(p4.y)+bf2f(p5.y)+bf2f(p6.y)+bf2f(p7.y);                      \
        ACC2 += bf2f(p0.z)+bf2f(p1.z)+bf2f(p2.z)+bf2f(p3.z)                       \
              + bf2f(p4.z)+bf2f(p5.z)+bf2f(p6.z)+bf2f(p7.z);                      \
        ACC3 += bf2f(p0.w)+bf2f(p1.w)+bf2f(p2.w)+bf2f(p3.w)                       \
              + bf2f(p4.w)+bf2f(p5.w)+bf2f(p6.w)+bf2f(p7.w);                      \
    }

// accumulate one 16B chunk (8 bf16) into 4 packed-f32 accumulators (k_lhat path)
__device__ __forceinline__ void accpk4(const uint4& d, f32x2& A0, f32x2& A1,
                                       f32x2& A2, f32x2& A3){
    f32x2 t;
    t.x = __uint_as_float(d.x << 16); t.y = __uint_as_float(d.x & 0xFFFF0000u); A0 += t;
    t.x = __uint_as_float(d.y << 16); t.y = __uint_as_float(d.y & 0xFFFF0000u); A1 += t;
    t.x = __uint_as_float(d.z << 16); t.y = __uint_as_float(d.z & 0xFFFF0000u); A2 += t;
    t.x = __uint_as_float(d.w << 16); t.y = __uint_as_float(d.w & 0xFFFF0000u); A3 += t;
}

// 16 neighbors x 16B per lane; two accumulator banks (k_lhat, r6-proven)
#define GATHER16X16(SRC, E0, E1, E2, E3, A0, A1, A2, A3, B0, B1, B2, B3, FO)      \
    {                                                                             \
        uint4 d0 = *(const uint4*)&SRC[(size_t)E0.x * NF + (FO)];                 \
        uint4 d1 = *(const uint4*)&SRC[(size_t)E0.y * NF + (FO)];                 \
        uint4 d2 = *(const uint4*)&SRC[(size_t)E0.z * NF + (FO)];                 \
        uint4 d3 = *(const uint4*)&SRC[(size_t)E0.w * NF + (FO)];                 \
        uint4 d4 = *(const uint4*)&SRC[(size_t)E1.x * NF + (FO)];                 \
        uint4 d5 = *(const uint4*)&SRC[(size_t)E1.y * NF + (FO)];                 \
        uint4 d6 = *(const uint4*)&SRC[(size_t)E1.z * NF + (FO)];                 \
        uint4 d7 = *(const uint4*)&SRC[(size_t)E1.w * NF + (FO)];                 \
        uint4 d8 = *(const uint4*)&SRC[(size_t)E2.x * NF + (FO)];                 \
        uint4 d9 = *(const uint4*)&SRC[(size_t)E2.y * NF + (FO)];                 \
        uint4 da = *(const uint4*)&SRC[(size_t)E2.z * NF + (FO)];                 \
        uint4 db = *(const uint4*)&SRC[(size_t)E2.w * NF + (FO)];                 \
        uint4 dc = *(const uint4*)&SRC[(size_t)E3.x * NF + (FO)];                 \
        uint4 dd = *(const uint4*)&SRC[(size_t)E3.y * NF + (FO)];                 \
        uint4 de = *(const uint4*)&SRC[(size_t)E3.z * NF + (FO)];                 \
        uint4 df = *(const uint4*)&SRC[(size_t)E3.w * NF + (FO)];                 \
        accpk4(d0, A0, A1, A2, A3); accpk4(d1, A0, A1, A2, A3);                   \
        accpk4(d2, A0, A1, A2, A3); accpk4(d3, A0, A1, A2, A3);                   \
        accpk4(d4, A0, A1, A2, A3); accpk4(d5, A0, A1, A2, A3);                   \
        accpk4(d6, A0, A1, A2, A3); accpk4(d7, A0, A1, A2, A3);                   \
        accpk4(d8, B0, B1, B2, B3); accpk4(d9, B0, B1, B2, B3);                   \
        accpk4(da, B0, B1, B2, B3); accpk4(db, B0, B1, B2, B3);                   \
        accpk4(dc, B0, B1, B2, B3); accpk4(dd, B0, B1, B2, B3);                   \
        accpk4(de, B0, B1, B2, B3); accpk4(df, B0, B1, B2, B3);                   \
    }

// fused setup grid (1636 blocks):
//   [0,625)      single edge pass: deg atomic + fillpad atomic (merged)
//   [625,1563)   buildv: float2 register transpose, 24 threads/node
//   1563         zero dummy rows
//   [1564,1636)  weight transposes
__global__ __launch_bounds__(256) void k_setup(
    const float* __restrict__ x, const int* __restrict__ ei,
    const float* __restrict__ chW, const float* __restrict__ tW, const float* __restrict__ rW,
    float* __restrict__ deg, int* __restrict__ cnt, int* __restrict__ csrp,
    unsigned short* __restrict__ vbf, unsigned short* __restrict__ tx1bf,
    unsigned short* __restrict__ cWt, unsigned short* __restrict__ rWtb,
    unsigned short* __restrict__ wkt)
{
    int bid = blockIdx.x, tid = threadIdx.x;
    if (bid < 625){
        int e = bid * 256 + tid;
        if (e < EE){
            int r = ei[e];
            int c = ei[EE + e];
            atomicAdd(&deg[r], 1.0f);
            int slot = atomicAdd(&cnt[c], 1);
            if (slot < SLOTS) csrp[c * SLOTS + slot] = r;
        }
    } else if (bid < 1563){
        int u = (bid - 625) * 256 + tid;             // < 240000
        if (u < 240000){
            int n = u / 24, r = u - n * 24;
            int t2 = r >> 2, j = r & 3;              // times {2t2, 2t2+1}, channels 4j..4j+3
            #pragma unroll
            for (int b = 0; b < BB; ++b){
                const float* xp = x + (size_t)(b * NN + n) * 192;
                float2 v0 = *(const float2*)&xp[(4 * j + 0) * 12 + 2 * t2];
                float2 v1 = *(const float2*)&xp[(4 * j + 1) * 12 + 2 * t2];
                float2 v2 = *(const float2*)&xp[(4 * j + 2) * 12 + 2 * t2];
                float2 v3 = *(const float2*)&xp[(4 * j + 3) * 12 + 2 * t2];
                ushort4 w0 = { f2bf(v0.x), f2bf(v1.x), f2bf(v2.x), f2bf(v3.x) };
                ushort4 w1 = { f2bf(v0.y), f2bf(v1.y), f2bf(v2.y), f2bf(v3.y) };
                size_t base = (size_t)n * NF + b * 192 + (2 * t2) * 16 + j * 4;
                *(ushort4*)&vbf[base]      = w0;
                *(ushort4*)&vbf[base + 16] = w1;
            }
        }
    } else if (bid == 1563){
        if (tid < 192){
            ushort4 z = { 0, 0, 0, 0 };
            *(ushort4*)&vbf[(size_t)NN * NF + tid * 4]   = z;
            *(ushort4*)&tx1bf[(size_t)NN * NF + tid * 4] = z;
        }
    } else {
        int idx = (bid - 1564) * 256 + tid;          // < 18432
        if (idx < 4096){                      // cWt[c][k], k = kk*16+f (48 real, pad 0)
            int c = idx >> 6, k = idx & 63;
            float v = 0.f;
            if (k < 48){ int kk = k >> 4, f = k & 15; v = chW[kk * 1024 + f * 64 + c]; }
            cWt[idx] = f2bf(v);
        } else if (idx < 6144){               // rWtb[o][k], k<16 = f, pad 0
            int j = idx - 4096;
            int o = j >> 5, k = j & 31;
            float v = (k < 16) ? rW[o * 16 + k] : 0.f;
            rWtb[j] = f2bf(v);
        } else {                              // wkt[kk][o][dc]
            int j = idx - 6144;
            int kk = j >> 12; int r2 = j & 4095;
            int o = r2 >> 6, dc = r2 & 63;
            wkt[j] = f2bf(tW[(o * 64 + dc) * 3 + kk]);
        }
    }
}

// tx1 = (2/lam)*(deg*v - agg) - v
// 2 nodes/block, 96 lanes/node, 16 neighbors x 16B in flight per lane.
// Trip count is BLOCK-uniform (max of both nodes); pad slots read the zero
// dummy row so extra iterations add exact 0 -> no wave divergence.
__global__ __launch_bounds__(192) void k_lhat(
        const unsigned short* __restrict__ vbf, const float* __restrict__ deg,
        const int* __restrict__ cnt, const int* __restrict__ csrp,
        const float* __restrict__ lam, unsigned short* __restrict__ tx1bf){
    int tid = threadIdx.x;
    int h  = tid >= 96;
    int fb = tid - h * 96;
    int n  = blockIdx.x * 2 + h;
    int fo = fb * 8;
    float s2 = 2.0f / lam[0];
    float dn = deg[n];
    int cA = cnt[blockIdx.x * 2];     cA = cA > SLOTS ? SLOTS : cA;
    int cB = cnt[blockIdx.x * 2 + 1]; cB = cB > SLOTS ? SLOTS : cB;
    int cm = cA > cB ? cA : cB;
    int iters = (cm + 15) >> 4;
    const int4* cp = (const int4*)(csrp + n * SLOTS);
    f32x2 A0 = {0.f,0.f}, A1 = {0.f,0.f}, A2 = {0.f,0.f}, A3 = {0.f,0.f};
    f32x2 B0 = {0.f,0.f}, B1 = {0.f,0.f}, B2 = {0.f,0.f}, B3 = {0.f,0.f};
    for (int it = 0; it < iters; ++it){
        int4 e0 = cp[it * 4], e1 = cp[it * 4 + 1];
        int4 e2 = cp[it * 4 + 2], e3 = cp[it * 4 + 3];
        GMIN4(e0) GMIN4(e1) GMIN4(e2) GMIN4(e3)
        GATHER16X16(vbf, e0, e1, e2, e3, A0, A1, A2, A3, B0, B1, B2, B3, fo);
    }
    A0 += B0; A1 += B1; A2 += B2; A3 += B3;
    uint4 hv = *(const uint4*)&vbf[(size_t)n * NF + fo];
    uint4 o;
    {
        float vlo, vhi;
        vlo = __uint_as_float(hv.x << 16); vhi = __uint_as_float(hv.x & 0xFFFF0000u);
        o.x = pk2bf(s2 * (dn * vlo - A0.x) - vlo, s2 * (dn * vhi - A0.y) - vhi);
        vlo = __uint_as_float(hv.y << 16); vhi = __uint_as_float(hv.y & 0xFFFF0000u);
        o.y = pk2bf(s2 * (dn * vlo - A1.x) - vlo, s2 * (dn * vhi - A1.y) - vhi);
        vlo = __uint_as_float(hv.z << 16); vhi = __uint_as_float(hv.z & 0xFFFF0000u);
        o.z = pk2bf(s2 * (dn * vlo - A2.x) - vlo, s2 * (dn * vhi - A2.y) - vhi);
        vlo = __uint_as_float(hv.w << 16); vhi = __uint_as_float(hv.w & 0xFFFF0000u);
        o.w = pk2bf(s2 * (dn * vlo - A3.x) - vlo, s2 * (dn * vhi - A3.y) - vhi);
    }
    *(uint4*)&tx1bf[(size_t)n * NF + fo] = o;
}

// per-node fused: gather->Tcat(bf16) -> MFMA Cheb+resid -> sp(bf16) -> MFMA
// temporal conv -> hmat -> LayerNorm -> out
// Phase A restored to the r1 89us configuration (8-deep, 8B/lane, 192 lanes,
// scalar unpack, weights loaded in phase B). LDS union 22016B.
__global__ __launch_bounds__(256) void k_fused(
    const unsigned short* __restrict__ vbf, const unsigned short* __restrict__ tx1bf,
    const float* __restrict__ deg, const int* __restrict__ cnt, const int* __restrict__ csrp,
    const float* __restrict__ lam,
    const unsigned short* __restrict__ cWt, const float* __restrict__ chebB,
    const unsigned short* __restrict__ wkt, const float* __restrict__ timeB,
    const unsigned short* __restrict__ rWtb, const float* __restrict__ resB,
    const float* __restrict__ gamma, const float* __restrict__ beta,
    float* __restrict__ out)
{
    __shared__ __align__(16) char smem[22016];
    unsigned short* spl  = (unsigned short*)smem;            // 56*SPS bf16 (phases B-D)
    float2*         red  = (float2*)smem;                    // 48 float2 (overlays dead spl)
    unsigned short* tcat = (unsigned short*)(smem + 8960);   // 48*TCS bf16 (phases A-B)
    float*          hmat = (float*)(smem + 8960);            // 48*HMS f32 (phase D+, overlays tcat)

    int n = blockIdx.x;
    int tid = threadIdx.x;

    int lane = tid & 63;
    int nt   = tid >> 6;
    int ln   = lane & 15;
    int quad = lane >> 4;
    int q8   = quad * 8;
    int col  = nt * 16 + ln;

    // ---- zero sp pad rows (p=0, p=13 per b) ----
    {
        int rid = tid >> 5;
        int cc = tid & 31;
        int b = rid >> 1, p = (rid & 1) * 13;
        *(unsigned int*)&spl[(b * 14 + p) * SPS + cc * 2] = 0u;
    }

    // ---- phase A: 8-way unrolled padded gather + build Tcat (bf16) ----
    if (tid < 192){
        float s2 = 2.0f / lam[0];
        float dn = deg[n];
        ushort4 hv = *(const ushort4*)&vbf[(size_t)n * NF + tid * 4];
        ushort4 hu = *(const ushort4*)&tx1bf[(size_t)n * NF + tid * 4];
        float a0 = 0.f, a1 = 0.f, a2 = 0.f, a3 = 0.f;
        int c = cnt[n]; c = c > SLOTS ? SLOTS : c;
        int iters = (c + 7) >> 3;
        const int4* cp = (const int4*)(csrp + n * SLOTS);
        for (int it = 0; it < iters; ++it){
            int4 e0 = cp[it * 2], e1 = cp[it * 2 + 1];
            GMIN4(e0) GMIN4(e1)
            GATHER8(tx1bf, e0, e1, a0, a1, a2, a3, tid);
        }
        float u0 = bf2f(hu.x), u1 = bf2f(hu.y), u2 = bf2f(hu.z), u3 = bf2f(hu.w);
        float v0 = bf2f(hv.x), v1 = bf2f(hv.y), v2 = bf2f(hv.z), v3 = bf2f(hv.w);
        ushort4 w2 = { f2bf(2.0f * (s2 * (dn * u0 - a0) - u0) - v0),
                       f2bf(2.0f * (s2 * (dn * u1 - a1) - u1) - v1),
                       f2bf(2.0f * (s2 * (dn * u2 - a2) - u2) - v2),
                       f2bf(2.0f * (s2 * (dn * u3 - a3) - u3) - v3) };
        ushort4 zz = { 0, 0, 0, 0 };
        int bt = tid >> 2, ch = tid & 3;
        *(ushort4*)&tcat[bt * TCS +      ch * 4] = hv;   // T0
        *(ushort4*)&tcat[bt * TCS + 16 + ch * 4] = hu;   // T1
        *(ushort4*)&tcat[bt * TCS + 32 + ch * 4] = w2;   // T2
        *(ushort4*)&tcat[bt * TCS + 48 + ch * 4] = zz;   // zero K-pad
    }
    __syncthreads();

    // ---- phase B: Cheb GEMM (K=64) + residual GEMM ----
    {
        bf16x8 cb0 = *(const bf16x8*)&cWt[col * 64 + q8];
        bf16x8 cb1 = *(const bf16x8*)&cWt[col * 64 + 32 + q8];
        bf16x8 rb  = *(const bf16x8*)&rWtb[col * 32 + q8];
        f32x4 cacc[3], racc[3];
        #pragma unroll
        for (int mt = 0; mt < 3; ++mt){
            bf16x8 a0 = *(const bf16x8*)&tcat[(mt * 16 + ln) * TCS + q8];
            bf16x8 a1 = *(const bf16x8*)&tcat[(mt * 16 + ln) * TCS + 32 + q8];
            f32x4 z = {0.f, 0.f, 0.f, 0.f};
            cacc[mt] = __builtin_amdgcn_mfma_f32_16x16x32_bf16(a0, cb0, z, 0, 0, 0);
            cacc[mt] = __builtin_amdgcn_mfma_f32_16x16x32_bf16(a1, cb1, cacc[mt], 0, 0, 0);
            racc[mt] = __builtin_amdgcn_mfma_f32_16x16x32_bf16(a0, rb, z, 0, 0, 0);
        }
        float cb = chebB[col];
        float tb = timeB[col] + resB[col];
        #pragma unroll
        for (int mt = 0; mt < 3; ++mt){
            #pragma unroll
            for (int i = 0; i < 4; ++i){
                int r = mt * 16 + quad * 4 + i;
                int bb = (r * 43) >> 9;
                int tt = r - 12 * bb;
                float val = fmaxf(cacc[mt][i] + cb, 0.0f);
                spl[(bb * 14 + tt + 1) * SPS + col] = f2bf(val);
            }
        }
        __syncthreads();   // tcat dead from here; hmat may overwrite it

        // ---- phase D: temporal conv = 3 shifted GEMMs ----
        bf16x8 wb[3][2];
        #pragma unroll
        for (int kk = 0; kk < 3; ++kk){
            wb[kk][0] = *(const bf16x8*)&wkt[kk * 4096 + col * 64 + q8];
            wb[kk][1] = *(const bf16x8*)&wkt[kk * 4096 + col * 64 + 32 + q8];
        }
        #pragma unroll
        for (int mt = 0; mt < 3; ++mt){
            int bt = mt * 16 + ln;
            int bb = (bt * 43) >> 9;
            int tt = bt - 12 * bb;
            int rbase = bb * 14 + tt;
            f32x4 tacc = {0.f, 0.f, 0.f, 0.f};
            #pragma unroll
            for (int kk = 0; kk < 3; ++kk){
                bf16x8 a0 = *(const bf16x8*)&spl[(rbase + kk) * SPS + q8];
                bf16x8 a1 = *(const bf16x8*)&spl[(rbase + kk) * SPS + 32 + q8];
                tacc = __builtin_amdgcn_mfma_f32_16x16x32_bf16(a0, wb[kk][0], tacc, 0, 0, 0);
                tacc = __builtin_amdgcn_mfma_f32_16x16x32_bf16(a1, wb[kk][1], tacc, 0, 0, 0);
            }
            #pragma unroll
            for (int i = 0; i < 4; ++i){
                int r = mt * 16 + quad * 4 + i;
                float h = fmaxf(tacc[i] + racc[mt][i] + tb, 0.0f);
                hmat[r * HMS + col] = h;
            }
        }
    }
    __syncthreads();   // spl dead from here; red may overwrite it

    // ---- LN partial sums: 4 lanes per row ----
    if (tid < 192){
        int row = tid >> 2, p = tid & 3;
        const float4* h4 = (const float4*)&hmat[row * HMS + p * 16];
        float4 A = h4[0], Bv = h4[1], Cv = h4[2], Dv = h4[3];
        float s = A.x+A.y+A.z+A.w + Bv.x+Bv.y+Bv.z+Bv.w
                + Cv.x+Cv.y+Cv.z+Cv.w + Dv.x+Dv.y+Dv.z+Dv.w;
        float q = A.x*A.x+A.y*A.y+A.z*A.z+A.w*A.w + Bv.x*Bv.x+Bv.y*Bv.y+Bv.z*Bv.z+Bv.w*Bv.w
                + Cv.x*Cv.x+Cv.y*Cv.y+Cv.z*Cv.z+Cv.w*Cv.w + Dv.x*Dv.x+Dv.y*Dv.y+Dv.z*Dv.z+Dv.w*Dv.w;
        s += __shfl_xor(s, 1); q += __shfl_xor(q, 1);
        s += __shfl_xor(s, 2); q += __shfl_xor(q, 2);
        if (p == 0) red[row] = make_float2(s, q);
    }
    __syncthreads();

    // ---- normalize + store ----
    {
        int g = nt, o = lane;
        float gam = gamma[o], bet = beta[o];
        float res[12];
        #pragma unroll
        for (int t = 0; t < 12; ++t){
            int row = g * 12 + t;
            float h = hmat[row * HMS + o];
            float2 m = red[row];
            float mu  = m.x * (1.0f / 64.0f);
            float var = m.y * (1.0f / 64.0f) - mu * mu;
            float r   = rsqrtf(var + 1e-5f);
            res[t] = (h - mu) * r * gam + bet;
        }
        size_t obase = ((size_t)(g * NN + n) * CCC + o) * TTT;
        float4* op = (float4*)(out + obase);
        op[0] = make_float4(res[0], res[1], res[2],  res[3]);
        op[1] = make_float4(res[4], res[5], res[6],  res[7]);
        op[2] = make_float4(res[8], res[9], res[10], res[11]);
    }
}

extern "C" void kernel_launch(void* const* d_in, const int* in_sizes, int n_in,
                              void* d_out, int out_size, void* d_ws, size_t ws_size,
                              hipStream_t stream)
{
    (void)in_sizes; (void)n_in; (void)out_size; (void)ws_size;
    const float* x   = (const float*)d_in[0];
    const int*   ei  = (const int*)  d_in[1];
    const float* lam = (const float*)d_in[2];
    const float* chW = (const float*)d_in[3];
    const float* chB = (const float*)d_in[4];
    const float* tW  = (const float*)d_in[5];
    const float* tB  = (const float*)d_in[6];
    const float* rW  = (const float*)d_in[7];
    const float* rB  = (const float*)d_in[8];
    const float* gam = (const float*)d_in[9];
    const float* bet = (const float*)d_in[10];
    float* out = (float*)d_out;

    char* ws = (char*)d_ws;
    float* deg  = (float*)(ws + WS_DEG);
    int*   cnt  = (int*)  (ws + WS_CNT);
    unsigned short* cWt  = (unsigned short*)(ws + WS_CWT);
    unsigned short* rWtb = (unsigned short*)(ws + WS_RWTB);
    unsigned short* wkt  = (unsigned short*)(ws + WS_WKT);
    int*   csrp = (int*)  (ws + WS_CSRP);
    unsigned short* vbf   = (unsigned short*)(ws + WS_VBF);
    unsigned short* tx1bf = (unsigned short*)(ws + WS_TX1BF);

    hipMemsetAsync(ws, 0, 81920, stream);                      // deg + cnt
    hipMemsetAsync(ws + WS_CSRP, 0x7F, NN * SLOTS * 4, stream); // csrp pad (clamped to NN)
    k_setup  <<<1636, 256, 0, stream>>>(x, ei, chW, tW, rW, deg, cnt, csrp,
                                        vbf, tx1bf, cWt, rWtb, wkt);
    k_lhat   <<<NN / 2, 192, 0, stream>>>(vbf, deg, cnt, csrp, lam, tx1bf);
    k_fused  <<<NN, 256, 0, stream>>>(vbf, tx1bf, deg, cnt, csrp, lam,
                                      cWt, chB, wkt, tB, rWtb, rB, gam, bet, out);
}